// Round 5
// baseline (68.259 us; speedup 1.0000x reference)
//
#include <hip/hip_runtime.h>
#include <math.h>

#define NS 96
#define NSEG 95
#define LPR 8      // lanes per ray
#define SPL 12     // segments per lane (8*12=96 slots, slot 95 fake)
#define RPB 32     // rays per block

__device__ __forceinline__ float fexp2(float x) { return __builtin_amdgcn_exp2f(x); }
__device__ __forceinline__ float flog2(float x) { return __builtin_amdgcn_logf(x); }

// ---------------------------------------------------------------------------
__global__ void init_mm_kernel(unsigned* mm) {
    mm[0] = 0x7F7FFFFFu;  // min accumulator (FLT_MAX bits)
    mm[1] = 0u;           // max accumulator (depths > 0)
}

// ---------------------------------------------------------------------------
// depths sorted along S: global min = min over rays of sample 0,
// global max = max over rays of sample 95.
// ---------------------------------------------------------------------------
__global__ __launch_bounds__(256) void minmax_kernel(
    const float* __restrict__ depths, unsigned* mm, int n_rays)
{
    int idx = blockIdx.x * blockDim.x + threadIdx.x;
    float lo = __int_as_float(0x7F7FFFFF);
    float hi = 0.0f;
    if (idx < n_rays) {
        lo = depths[(size_t)idx * NS];
        hi = depths[(size_t)idx * NS + (NS - 1)];
    }
#pragma unroll
    for (int off = 32; off; off >>= 1) {
        lo = fminf(lo, __shfl_xor(lo, off));
        hi = fmaxf(hi, __shfl_xor(hi, off));
    }
    if ((threadIdx.x & 63) == 0) {
        atomicMin(&mm[0], __float_as_uint(lo));
        atomicMax(&mm[1], __float_as_uint(hi));
    }
}

// ---------------------------------------------------------------------------
// Phase A: dep/den direct float4 loads; weights, scan, depth composite.
// Colors: 9 coalesced float4 loads issued at kernel top, kept in flight
// under phase A (sched_barrier + asm liveness pins), staged to LDS, then
// consumed per-lane in phase B. One __syncthreads total.
// ---------------------------------------------------------------------------
__global__ __launch_bounds__(256) void raymarch_kernel(
    const float4* __restrict__ col4,
    const float* __restrict__ densities,
    const float* __restrict__ depths,
    const unsigned* __restrict__ mm,
    float* __restrict__ out_rgb,
    float* __restrict__ out_depth,
    float* __restrict__ out_w,
    int n_rays)
{
    __shared__ float4 sc[RPB * 73];    // 37376 B -> 4 blocks/CU

    const int tid  = threadIdx.x;
    const int base = blockIdx.x * RPB;
    const int lane = tid & 63;
    const int sub  = lane & 7;
    const int rloc = (tid >> 6) * 8 + (lane >> 3);
    const int ray  = base + rloc;
    const int rc   = min(ray, n_rays - 1);
    const bool safe = (ray < n_rays);

    const int s0 = sub * SPL;
    const float* dep = depths    + (size_t)rc * NS + s0;
    const float* den = densities + (size_t)rc * NS + s0;

    // ---- issue dep/den loads (needed first) --------------------------------
    float4 dv[3], nv[3];
#pragma unroll
    for (int q = 0; q < 3; ++q) {
        dv[q] = *(const float4*)(dep + 4 * q);
        nv[q] = *(const float4*)(den + 4 * q);
    }
    const int i13 = (sub == 7) ? 11 : 12;   // clamp: delta=0 -> e=1 -> w=0
    float d12  = dep[i13];
    float nd12 = den[i13];

    // ---- issue coalesced color loads for the whole 32-ray tile -------------
    const float4* gc = col4 + (size_t)base * 72;
    const int nf4 = (min(base + RPB, n_rays) - base) * 72;
    float4 cf[9];
#pragma unroll
    for (int q = 0; q < 9; ++q) {
        int f = tid + 256 * q;
        cf[q] = (f < nf4) ? gc[f] : make_float4(0.f, 0.f, 0.f, 0.f);
    }
    // keep all loads issued above this point; nothing sinks past here
    __builtin_amdgcn_sched_barrier(0);

    // ======================= Phase A ========================================
    float d[13], nd[13];
#pragma unroll
    for (int q = 0; q < 3; ++q) {
        d[4*q+0] = dv[q].x; d[4*q+1] = dv[q].y; d[4*q+2] = dv[q].z; d[4*q+3] = dv[q].w;
        nd[4*q+0] = nv[q].x; nd[4*q+1] = nv[q].y; nd[4*q+2] = nv[q].z; nd[4*q+3] = nv[q].w;
    }
    d[12] = d12; nd[12] = nd12;

    const float LOG2E = 1.4426950408889634f;
    float e[SPL];
#pragma unroll
    for (int j = 0; j < SPL; ++j) {
        float delta = d[j+1] - d[j];
        float x = (nd[j] + nd[j+1]) * 0.5f - 1.0f;
        float sp2 = fmaxf(x, 0.f) * LOG2E + flog2(1.0f + fexp2(-fabsf(x) * LOG2E));
        e[j] = fexp2(-delta * sp2);
    }

    // local product + width-8 inclusive scan -> exclusive transmittance
    float P = 1.0f;
#pragma unroll
    for (int j = 0; j < SPL; ++j) P *= (e[j] + 1e-10f);
    float inc = P;
#pragma unroll
    for (int off = 1; off < LPR; off <<= 1) {
        float t = __shfl_up(inc, off, LPR);
        if (sub >= off) inc *= t;
    }
    float Tex = __shfl_up(inc, 1, LPR);
    if (sub == 0) Tex = 1.0f;

    // weights + weight/depth composites + out_w stores
    float w[SPL];
    float* wg = out_w + (size_t)rc * NSEG + s0;
    float sw = 0.f, sd = 0.f;
    {
        float T = Tex;
#pragma unroll
        for (int j = 0; j < SPL; ++j) {
            w[j] = (1.0f - e[j]) * T;
            T *= (e[j] + 1e-10f);
            sw += w[j];
            sd += w[j] * ((d[j] + d[j+1]) * 0.5f);
            if (safe && (sub < 7 || j < 11)) wg[j] = w[j];
        }
    }
#pragma unroll
    for (int off = 1; off < LPR; off <<= 1) {
        sw += __shfl_xor(sw, off, LPR);
        sd += __shfl_xor(sd, off, LPR);
    }
    if (sub == 0 && safe) {
        float cd = sd / sw;
        if (isnan(cd)) cd = __int_as_float(0x7F800000);
        cd = fminf(fmaxf(cd, __uint_as_float(mm[0])), __uint_as_float(mm[1]));
        out_depth[ray] = cd;
    }

    // ---- pin colors live (loads stayed in flight under phase A) ------------
#pragma unroll
    for (int q = 0; q < 9; ++q) {
        asm volatile("" :: "v"(cf[q].x), "v"(cf[q].y), "v"(cf[q].z), "v"(cf[q].w));
    }
    // stage colors to LDS (padded stride 73 f4 per ray)
#pragma unroll
    for (int q = 0; q < 9; ++q) {
        int f = tid + 256 * q;
        int r = f / 72;
        sc[r * 73 + (f - 72 * r)] = cf[q];
    }
    __syncthreads();

    // ======================= Phase B ========================================
    const float* lcol = (const float*)&sc[rloc * 73];
    float c[40];
#pragma unroll
    for (int q = 0; q < 10; ++q) {
        float4 v = *(const float4*)(lcol + sub * 36 + 4 * q);
        c[4*q+0] = v.x; c[4*q+1] = v.y; c[4*q+2] = v.z; c[4*q+3] = v.w;
    }
    if (sub == 7) { c[36] = c[37] = c[38] = c[39] = 0.0f; }

    float sr = 0.f, sg = 0.f, sb = 0.f;
#pragma unroll
    for (int j = 0; j < SPL; ++j) {
        sr += w[j] * (c[3*j+0] + c[3*j+3]);
        sg += w[j] * (c[3*j+1] + c[3*j+4]);
        sb += w[j] * (c[3*j+2] + c[3*j+5]);
    }
#pragma unroll
    for (int off = 1; off < LPR; off <<= 1) {
        sr += __shfl_xor(sr, off, LPR);
        sg += __shfl_xor(sg, off, LPR);
        sb += __shfl_xor(sb, off, LPR);
    }
    if (sub == 0 && safe) {
        out_rgb[(size_t)ray * 3 + 0] = sr - 1.0f;   // (0.5*sr)*2 - 1
        out_rgb[(size_t)ray * 3 + 1] = sg - 1.0f;
        out_rgb[(size_t)ray * 3 + 2] = sb - 1.0f;
    }
}

// ---------------------------------------------------------------------------
extern "C" void kernel_launch(void* const* d_in, const int* in_sizes, int n_in,
                              void* d_out, int out_size, void* d_ws, size_t ws_size,
                              hipStream_t stream) {
    const float* colors    = (const float*)d_in[0];
    const float* densities = (const float*)d_in[1];
    const float* depths    = (const float*)d_in[2];

    const int n_rays = in_sizes[1] / NS;

    float* out       = (float*)d_out;
    float* out_rgb   = out;
    float* out_depth = out + (size_t)n_rays * 3;
    float* out_w     = out + (size_t)n_rays * 4;

    unsigned* mm = (unsigned*)d_ws;

    hipLaunchKernelGGL(init_mm_kernel, dim3(1), dim3(1), 0, stream, mm);
    hipLaunchKernelGGL(minmax_kernel, dim3((n_rays + 255) / 256), dim3(256), 0,
                       stream, depths, mm, n_rays);
    hipLaunchKernelGGL(raymarch_kernel,
                       dim3((n_rays + RPB - 1) / RPB), dim3(256), 0, stream,
                       (const float4*)colors, densities, depths, mm,
                       out_rgb, out_depth, out_w, n_rays);
}

// Round 6
// 38.207 us; speedup vs baseline: 1.7866x; 1.7866x over previous
//
#include <hip/hip_runtime.h>
#include <math.h>

#define NS 96
#define NSEG 95
#define LPR 16     // lanes per ray
#define SPL 6      // segments per lane (16*6 = 96 slots, slot 95 fake)
#define RPB 16     // rays per block (256 threads / 16 lanes)

__device__ __forceinline__ float fexp2(float x) { return __builtin_amdgcn_exp2f(x); }
__device__ __forceinline__ float flog2(float x) { return __builtin_amdgcn_logf(x); }

// ---------------------------------------------------------------------------
__global__ void init_mm_kernel(unsigned* mm) {
    mm[0] = 0x7F7FFFFFu;  // min accumulator (FLT_MAX bits)
    mm[1] = 0u;           // max accumulator (depths > 0)
}

// ---------------------------------------------------------------------------
// Global min/max of depths. Sorted along S, so min lives in samples 0..3 and
// max in samples 92..95 of each ray: 2 float4 loads per ray (8 MB of lines
// instead of a 25 MB full sweep).
// ---------------------------------------------------------------------------
__global__ __launch_bounds__(256) void minmax_kernel(
    const float4* __restrict__ dep4, unsigned* mm, int n_rays)
{
    __shared__ float slo[4], shi[4];
    const int stride = gridDim.x * blockDim.x;
    float lo = __int_as_float(0x7F7FFFFF), hi = 0.0f;
    for (int ray = blockIdx.x * blockDim.x + threadIdx.x; ray < n_rays; ray += stride) {
        float4 a = dep4[(size_t)ray * 24];        // samples 0..3
        float4 b = dep4[(size_t)ray * 24 + 23];   // samples 92..95
        lo = fminf(lo, fminf(fminf(a.x, a.y), fminf(a.z, a.w)));
        hi = fmaxf(hi, fmaxf(fmaxf(b.x, b.y), fmaxf(b.z, b.w)));
    }
#pragma unroll
    for (int off = 32; off; off >>= 1) {
        lo = fminf(lo, __shfl_xor(lo, off));
        hi = fmaxf(hi, __shfl_xor(hi, off));
    }
    const int wv = threadIdx.x >> 6;
    if ((threadIdx.x & 63) == 0) { slo[wv] = lo; shi[wv] = hi; }
    __syncthreads();
    if (threadIdx.x == 0) {
        lo = fminf(fminf(slo[0], slo[1]), fminf(slo[2], slo[3]));
        hi = fmaxf(fmaxf(shi[0], shi[1]), fmaxf(shi[2], shi[3]));
        atomicMin(&mm[0], __float_as_uint(lo));
        atomicMax(&mm[1], __float_as_uint(hi));
    }
}

// ---------------------------------------------------------------------------
// 16 lanes per ray, 6 segments per lane. No LDS, no barriers; small state so
// all loads stay batched in flight. Fake segment 95 handled by clamped
// addresses (delta = 0 -> e = 1 -> w = 0 exactly, any finite color is ok).
// ---------------------------------------------------------------------------
__global__ __launch_bounds__(256, 5) void raymarch_kernel(
    const float* __restrict__ colors,
    const float* __restrict__ densities,
    const float* __restrict__ depths,
    const unsigned* __restrict__ mm,
    float* __restrict__ out_rgb,
    float* __restrict__ out_depth,
    float* __restrict__ out_w,
    int n_rays)
{
    const int tid  = threadIdx.x;
    const int lane = tid & 63;
    const int sub  = lane & 15;                    // lane within ray (0..15)
    const int rloc = (tid >> 6) * 4 + (lane >> 4); // ray within block (0..15)
    const int ray  = blockIdx.x * RPB + rloc;
    if (ray >= n_rays) return;

    const int s0 = sub * SPL;                      // first sample (0,6,..,90)
    const bool lastl = (sub == LPR - 1);

    const float* dep = depths    + (size_t)ray * NS + s0;
    const float* den = densities + (size_t)ray * NS + s0;
    const float* col = colors    + (size_t)ray * NS * 3 + 3 * s0;

    // ---- depths / densities: 3 float2 + 1 clamped scalar each -------------
    float d[7], nd[7];
    {
        float2 v;
        v = *(const float2*)(dep + 0); d[0] = v.x; d[1] = v.y;
        v = *(const float2*)(dep + 2); d[2] = v.x; d[3] = v.y;
        v = *(const float2*)(dep + 4); d[4] = v.x; d[5] = v.y;
        d[6] = dep[lastl ? 5 : 6];     // lastl: d[6]=d[5] -> delta=0 -> w=0
        v = *(const float2*)(den + 0); nd[0] = v.x; nd[1] = v.y;
        v = *(const float2*)(den + 2); nd[2] = v.x; nd[3] = v.y;
        v = *(const float2*)(den + 4); nd[4] = v.x; nd[5] = v.y;
        nd[6] = den[lastl ? 5 : 6];
    }

    // ---- colors: 21 floats (9 f2 + 1 clamped f2 + 1 clamped scalar) --------
    float c[21];
#pragma unroll
    for (int q = 0; q < 9; ++q) {
        float2 v = *(const float2*)(col + 2 * q);
        c[2 * q] = v.x; c[2 * q + 1] = v.y;
    }
    {
        float2 v = *(const float2*)(col + (lastl ? 16 : 18));
        c[18] = v.x; c[19] = v.y;          // lastl: dup of c[16..17], w=0 kills
        c[20] = col[lastl ? 17 : 20];
    }

    // ---- e_j = exp(-softplus(mid-1)*delta), native exp2/log2 ---------------
    const float LOG2E = 1.4426950408889634f;
    float e[SPL];
#pragma unroll
    for (int j = 0; j < SPL; ++j) {
        float delta = d[j + 1] - d[j];
        float x = (nd[j] + nd[j + 1]) * 0.5f - 1.0f;
        float sp2 = fmaxf(x, 0.f) * LOG2E + flog2(1.0f + fexp2(-fabsf(x) * LOG2E));
        e[j] = fexp2(-delta * sp2);
    }

    // ---- local product + width-16 inclusive scan -> exclusive T ------------
    float P = 1.0f;
#pragma unroll
    for (int j = 0; j < SPL; ++j) P *= (e[j] + 1e-10f);
    float inc = P;
#pragma unroll
    for (int off = 1; off < LPR; off <<= 1) {
        float t = __shfl_up(inc, off, LPR);
        if (sub >= off) inc *= t;
    }
    float Tex = __shfl_up(inc, 1, LPR);
    if (sub == 0) Tex = 1.0f;

    // ---- weights, composites, weight stores --------------------------------
    float w[SPL];
    float sw = 0.f, sd = 0.f;
    {
        float T = Tex;
#pragma unroll
        for (int j = 0; j < SPL; ++j) {
            w[j] = (1.0f - e[j]) * T;
            T *= (e[j] + 1e-10f);
            sw += w[j];
            sd += w[j] * ((d[j] + d[j + 1]) * 0.5f);
        }
    }
    float* wg = out_w + (size_t)ray * NSEG + s0;
#pragma unroll
    for (int j = 0; j < SPL - 1; ++j) wg[j] = w[j];
    if (!lastl) wg[SPL - 1] = w[SPL - 1];   // slot 95 doesn't exist

    // ---- rgb partials ------------------------------------------------------
    float sr = 0.f, sg = 0.f, sb = 0.f;
#pragma unroll
    for (int j = 0; j < SPL; ++j) {
        sr += w[j] * (c[3 * j + 0] + c[3 * j + 3]);
        sg += w[j] * (c[3 * j + 1] + c[3 * j + 4]);
        sb += w[j] * (c[3 * j + 2] + c[3 * j + 5]);
    }

    // ---- width-16 butterflies for the 5 composites -------------------------
#pragma unroll
    for (int off = 1; off < LPR; off <<= 1) {
        sw += __shfl_xor(sw, off, LPR);
        sd += __shfl_xor(sd, off, LPR);
        sr += __shfl_xor(sr, off, LPR);
        sg += __shfl_xor(sg, off, LPR);
        sb += __shfl_xor(sb, off, LPR);
    }

    if (sub == 0) {
        float cd = sd / sw;
        if (isnan(cd)) cd = __int_as_float(0x7F800000);
        cd = fminf(fmaxf(cd, __uint_as_float(mm[0])), __uint_as_float(mm[1]));
        out_depth[ray] = cd;
        out_rgb[(size_t)ray * 3 + 0] = sr - 1.0f;   // (0.5*sr)*2 - 1
        out_rgb[(size_t)ray * 3 + 1] = sg - 1.0f;
        out_rgb[(size_t)ray * 3 + 2] = sb - 1.0f;
    }
}

// ---------------------------------------------------------------------------
extern "C" void kernel_launch(void* const* d_in, const int* in_sizes, int n_in,
                              void* d_out, int out_size, void* d_ws, size_t ws_size,
                              hipStream_t stream) {
    const float* colors    = (const float*)d_in[0];
    const float* densities = (const float*)d_in[1];
    const float* depths    = (const float*)d_in[2];

    const int n_rays = in_sizes[1] / NS;

    float* out       = (float*)d_out;
    float* out_rgb   = out;
    float* out_depth = out + (size_t)n_rays * 3;
    float* out_w     = out + (size_t)n_rays * 4;

    unsigned* mm = (unsigned*)d_ws;

    hipLaunchKernelGGL(init_mm_kernel, dim3(1), dim3(1), 0, stream, mm);
    hipLaunchKernelGGL(minmax_kernel, dim3(128), dim3(256), 0, stream,
                       (const float4*)depths, mm, n_rays);
    hipLaunchKernelGGL(raymarch_kernel,
                       dim3((n_rays + RPB - 1) / RPB), dim3(256), 0, stream,
                       colors, densities, depths, mm,
                       out_rgb, out_depth, out_w, n_rays);
}

// Round 7
// 37.808 us; speedup vs baseline: 1.8054x; 1.0106x over previous
//
#include <hip/hip_runtime.h>
#include <math.h>

#define NS 96
#define NSEG 95
#define LPR 16     // lanes per ray
#define SPL 6      // segments per lane (16*6 = 96 slots, slot 95 fake)
#define RPB 16     // rays per block (256 threads / 16 lanes)

__device__ __forceinline__ float fexp2(float x) { return __builtin_amdgcn_exp2f(x); }
__device__ __forceinline__ float flog2(float x) { return __builtin_amdgcn_logf(x); }

// ---------------------------------------------------------------------------
// Global min/max of depths. Sorted along S, so min lives in samples 0..3 and
// max in samples 92..95 of each ray. Both accumulators are zero-initialized
// (hipMemsetAsync); min uses complement encoding: atomicMax(~bits(x)), valid
// because depths > 0 (bits monotone, ~bits reverses order).
// ---------------------------------------------------------------------------
__global__ __launch_bounds__(256) void minmax_kernel(
    const float4* __restrict__ dep4, unsigned* mm, int n_rays)
{
    __shared__ float slo[4], shi[4];
    const int stride = gridDim.x * blockDim.x;
    float lo = __int_as_float(0x7F7FFFFF), hi = 0.0f;
    for (int ray = blockIdx.x * blockDim.x + threadIdx.x; ray < n_rays; ray += stride) {
        float4 a = dep4[(size_t)ray * 24];        // samples 0..3
        float4 b = dep4[(size_t)ray * 24 + 23];   // samples 92..95
        lo = fminf(lo, fminf(fminf(a.x, a.y), fminf(a.z, a.w)));
        hi = fmaxf(hi, fmaxf(fmaxf(b.x, b.y), fmaxf(b.z, b.w)));
    }
#pragma unroll
    for (int off = 32; off; off >>= 1) {
        lo = fminf(lo, __shfl_xor(lo, off));
        hi = fmaxf(hi, __shfl_xor(hi, off));
    }
    const int wv = threadIdx.x >> 6;
    if ((threadIdx.x & 63) == 0) { slo[wv] = lo; shi[wv] = hi; }
    __syncthreads();
    if (threadIdx.x == 0) {
        lo = fminf(fminf(slo[0], slo[1]), fminf(slo[2], slo[3]));
        hi = fmaxf(fmaxf(shi[0], shi[1]), fmaxf(shi[2], shi[3]));
        atomicMax(&mm[0], ~__float_as_uint(lo));   // complement-encoded min
        atomicMax(&mm[1], __float_as_uint(hi));
    }
}

// ---------------------------------------------------------------------------
// 16 lanes per ray, 6 segments per lane. No LDS, no barriers; small state so
// all loads stay batched in flight. Fake segment 95 handled by clamped
// addresses (delta = 0 -> e = 1 -> w = 0 exactly, any finite color is ok).
// ---------------------------------------------------------------------------
__global__ __launch_bounds__(256, 5) void raymarch_kernel(
    const float* __restrict__ colors,
    const float* __restrict__ densities,
    const float* __restrict__ depths,
    const unsigned* __restrict__ mm,
    float* __restrict__ out_rgb,
    float* __restrict__ out_depth,
    float* __restrict__ out_w,
    int n_rays)
{
    const int tid  = threadIdx.x;
    const int lane = tid & 63;
    const int sub  = lane & 15;                    // lane within ray (0..15)
    const int rloc = (tid >> 6) * 4 + (lane >> 4); // ray within block (0..15)
    const int ray  = blockIdx.x * RPB + rloc;
    if (ray >= n_rays) return;

    const int s0 = sub * SPL;                      // first sample (0,6,..,90)
    const bool lastl = (sub == LPR - 1);

    const float* dep = depths    + (size_t)ray * NS + s0;
    const float* den = densities + (size_t)ray * NS + s0;
    const float* col = colors    + (size_t)ray * NS * 3 + 3 * s0;

    // ---- depths / densities: 3 float2 + 1 clamped scalar each -------------
    float d[7], nd[7];
    {
        float2 v;
        v = *(const float2*)(dep + 0); d[0] = v.x; d[1] = v.y;
        v = *(const float2*)(dep + 2); d[2] = v.x; d[3] = v.y;
        v = *(const float2*)(dep + 4); d[4] = v.x; d[5] = v.y;
        d[6] = dep[lastl ? 5 : 6];     // lastl: d[6]=d[5] -> delta=0 -> w=0
        v = *(const float2*)(den + 0); nd[0] = v.x; nd[1] = v.y;
        v = *(const float2*)(den + 2); nd[2] = v.x; nd[3] = v.y;
        v = *(const float2*)(den + 4); nd[4] = v.x; nd[5] = v.y;
        nd[6] = den[lastl ? 5 : 6];
    }

    // ---- colors: 21 floats (9 f2 + 1 clamped f2 + 1 clamped scalar) --------
    float c[21];
#pragma unroll
    for (int q = 0; q < 9; ++q) {
        float2 v = *(const float2*)(col + 2 * q);
        c[2 * q] = v.x; c[2 * q + 1] = v.y;
    }
    {
        float2 v = *(const float2*)(col + (lastl ? 16 : 18));
        c[18] = v.x; c[19] = v.y;          // lastl: dup of c[16..17], w=0 kills
        c[20] = col[lastl ? 17 : 20];
    }

    // ---- e_j = exp(-softplus(mid-1)*delta), native exp2/log2 ---------------
    const float LOG2E = 1.4426950408889634f;
    float e[SPL];
#pragma unroll
    for (int j = 0; j < SPL; ++j) {
        float delta = d[j + 1] - d[j];
        float x = (nd[j] + nd[j + 1]) * 0.5f - 1.0f;
        float sp2 = fmaxf(x, 0.f) * LOG2E + flog2(1.0f + fexp2(-fabsf(x) * LOG2E));
        e[j] = fexp2(-delta * sp2);
    }

    // ---- local product + width-16 inclusive scan -> exclusive T ------------
    float P = 1.0f;
#pragma unroll
    for (int j = 0; j < SPL; ++j) P *= (e[j] + 1e-10f);
    float inc = P;
#pragma unroll
    for (int off = 1; off < LPR; off <<= 1) {
        float t = __shfl_up(inc, off, LPR);
        if (sub >= off) inc *= t;
    }
    float Tex = __shfl_up(inc, 1, LPR);
    if (sub == 0) Tex = 1.0f;

    // ---- weights, composites --------------------------------------------
    float w[SPL];
    float sw = 0.f, sd = 0.f;
    {
        float T = Tex;
#pragma unroll
        for (int j = 0; j < SPL; ++j) {
            w[j] = (1.0f - e[j]) * T;
            T *= (e[j] + 1e-10f);
            sw += w[j];
            sd += w[j] * (d[j] + d[j + 1]);   // x0.5 folded into epilogue
        }
    }

    // ---- weight stores: 3x float2 (wg is 8B-aligned: s0*4 = 24B*sub) ------
    float* wg = out_w + (size_t)ray * NSEG + s0;
    *(float2*)(wg + 0) = make_float2(w[0], w[1]);
    *(float2*)(wg + 2) = make_float2(w[2], w[3]);
    if (!lastl) {
        *(float2*)(wg + 4) = make_float2(w[4], w[5]);
    } else {
        wg[4] = w[4];                      // slot 95 doesn't exist
    }

    // ---- rgb partials ------------------------------------------------------
    float sr = 0.f, sg = 0.f, sb = 0.f;
#pragma unroll
    for (int j = 0; j < SPL; ++j) {
        sr += w[j] * (c[3 * j + 0] + c[3 * j + 3]);
        sg += w[j] * (c[3 * j + 1] + c[3 * j + 4]);
        sb += w[j] * (c[3 * j + 2] + c[3 * j + 5]);
    }

    // ---- width-16 butterflies for the 5 composites -------------------------
#pragma unroll
    for (int off = 1; off < LPR; off <<= 1) {
        sw += __shfl_xor(sw, off, LPR);
        sd += __shfl_xor(sd, off, LPR);
        sr += __shfl_xor(sr, off, LPR);
        sg += __shfl_xor(sg, off, LPR);
        sb += __shfl_xor(sb, off, LPR);
    }

    if (sub == 0) {
        float cd = (0.5f * sd) / sw;
        if (isnan(cd)) cd = __int_as_float(0x7F800000);
        float gmin = __uint_as_float(~mm[0]);   // decode complement min
        float gmax = __uint_as_float(mm[1]);
        cd = fminf(fmaxf(cd, gmin), gmax);
        out_depth[ray] = cd;
        out_rgb[(size_t)ray * 3 + 0] = sr - 1.0f;   // (0.5*sr)*2 - 1
        out_rgb[(size_t)ray * 3 + 1] = sg - 1.0f;
        out_rgb[(size_t)ray * 3 + 2] = sb - 1.0f;
    }
}

// ---------------------------------------------------------------------------
extern "C" void kernel_launch(void* const* d_in, const int* in_sizes, int n_in,
                              void* d_out, int out_size, void* d_ws, size_t ws_size,
                              hipStream_t stream) {
    const float* colors    = (const float*)d_in[0];
    const float* densities = (const float*)d_in[1];
    const float* depths    = (const float*)d_in[2];

    const int n_rays = in_sizes[1] / NS;

    float* out       = (float*)d_out;
    float* out_rgb   = out;
    float* out_depth = out + (size_t)n_rays * 3;
    float* out_w     = out + (size_t)n_rays * 4;

    unsigned* mm = (unsigned*)d_ws;

    hipMemsetAsync(mm, 0, 2 * sizeof(unsigned), stream);
    hipLaunchKernelGGL(minmax_kernel, dim3(128), dim3(256), 0, stream,
                       (const float4*)depths, mm, n_rays);
    hipLaunchKernelGGL(raymarch_kernel,
                       dim3((n_rays + RPB - 1) / RPB), dim3(256), 0, stream,
                       colors, densities, depths, mm,
                       out_rgb, out_depth, out_w, n_rays);
}